// Round 7
// baseline (10276.856 us; speedup 1.0000x reference)
//
#include <hip/hip_runtime.h>
#include <cmath>

#define BB 64
#define TT 2048
#define FF 64
#define HH 160
#define G3 480
#define TC 256            // time-chunk length
#define NC (TT / TC)      // 8 chunks

typedef unsigned int u32;
typedef _Float16 half8 __attribute__((ext_vector_type(8)));
typedef float f32x4 __attribute__((ext_vector_type(4)));

__device__ __forceinline__ unsigned short f2h(float v) {
    _Float16 h = (_Float16)v;
    return __builtin_bit_cast(unsigned short, h);
}
__device__ __forceinline__ u32 packh2(float a, float b) {
    return (u32)f2h(a) | ((u32)f2h(b) << 16);
}
__device__ __forceinline__ float fsigmoid(float v) { return 1.f / (1.f + __expf(-v)); }
__device__ __forceinline__ float ftanhf(float v) {
    float xc = fminf(fmaxf(v, -15.f), 15.f);
    float e = __expf(2.f * xc);
    return 1.f - 2.f / (e + 1.f);
}
__device__ __forceinline__ float gelu_exact(float v) {
    return 0.5f * v * (1.f + erff(v * 0.70710678118654752f));
}
// 8 consecutive f32 -> half8 (MFMA fragment order: element j = k-index j)
__device__ __forceinline__ half8 load_wrow8(const float* p) {
    const float4* q = (const float4*)p;
    float4 a = q[0], b = q[1];
    half8 r;
    r[0] = (_Float16)a.x; r[1] = (_Float16)a.y; r[2] = (_Float16)a.z; r[3] = (_Float16)a.w;
    r[4] = (_Float16)b.x; r[5] = (_Float16)b.y; r[6] = (_Float16)b.z; r[7] = (_Float16)b.w;
    return r;
}
#define MM16(A_, B_, C_) __builtin_amdgcn_mfma_f32_16x16x32_f16(A_, B_, C_, 0, 0, 0)

// ---------------------------------------------------------------------------
// K1: dilated conv + BN + exact GELU -> z f16 [B/16][T][16 chains][64] (u32 pairs)
// ---------------------------------------------------------------------------
__global__ __launch_bounds__(256) void conv_bn_gelu_kernel(
    const float* __restrict__ x, const float* __restrict__ mix_w,
    const float* __restrict__ bn_g, const float* __restrict__ bn_b,
    const float* __restrict__ bn_m, const float* __restrict__ bn_v,
    u32* __restrict__ z_out)
{
    __shared__ float ws_w[3][64][64];
    __shared__ float ws_x[132][64];
    const int b  = blockIdx.y;
    const int t0 = blockIdx.x * 128;
    const int tid = threadIdx.x;
    const int f  = tid & 63;
    const int rg = tid >> 6;

    for (int idx = tid; idx < 64 * 64 * 3; idx += 256) {
        int fo = idx / 192;
        int rem = idx - fo * 192;
        int fi = rem / 3;
        int k  = rem - fi * 3;
        ws_w[k][fi][fo] = mix_w[idx];
    }
    for (int row = rg; row < 132; row += 4) {
        int t = t0 - 2 + row;
        ws_x[row][f] = (t >= 0 && t < TT) ? x[((size_t)b * TT + t) * FF + f] : 0.f;
    }
    __syncthreads();

    const float scale = bn_g[f] * rsqrtf(bn_v[f] + 1e-5f);
    const float shift = bn_b[f] - bn_m[f] * scale;

    for (int ti = rg; ti < 128; ti += 4) {
        float acc = 0.f;
        #pragma unroll
        for (int k = 0; k < 3; ++k) {
            const float* xr = &ws_x[ti + 2 * k][0];
            #pragma unroll
            for (int fi = 0; fi < 64; ++fi)
                acc = fmaf(xr[fi], ws_w[k][fi][f], acc);
        }
        float y = fmaf(acc, scale, shift);
        float z = gelu_exact(y);
        float zp = __shfl_xor(z, 1);
        if ((f & 1) == 0)
            z_out[(((size_t)(b >> 4) * TT + (t0 + ti)) * 16 + (b & 15)) * 32 + (f >> 1)]
                = packh2(z, zp);
    }
}

// ---------------------------------------------------------------------------
// K2: xg GEMM via MFMA. D[n',chain] = W·in_t^T + bias, written as
// xg[t][tile0..29][chain 0..15][n' 0..15] f32 (scan-friendly, all coalesced).
// grid (TC/TG, 4 blkB), block 512 (8 waves, wave w owns tiles 4w..4w+3).
// ---------------------------------------------------------------------------
#define DECLAI(i) half8 A##i##_0, A##i##_1, A##i##_2, A##i##_3, A##i##_4;
#define GLOADA(i) { int tl = wv4 + (i); int rowc = tl < 30 ? tl * 16 + lane15 : 479; \
    const float* wp = W + (size_t)rowc * K + quad * 8;                               \
    A##i##_0 = load_wrow8(wp); A##i##_1 = load_wrow8(wp + 32);                       \
    if (KT > 2) { A##i##_2 = load_wrow8(wp + 64); A##i##_3 = load_wrow8(wp + 96);    \
                  A##i##_4 = load_wrow8(wp + 128); }                                 \
    else { A##i##_2 = A##i##_0; A##i##_3 = A##i##_0; A##i##_4 = A##i##_0; } }
#define GMM(i, kt) C##i = MM16(A##i##_##kt, Bk##kt, C##i);

template<int K, int KT, int TG>
__global__ __launch_bounds__(512) void xg_gemm_mfma(
    const unsigned short* __restrict__ in,  // f16 [blk][rows][16 chains][K]
    size_t in_blk_stride, int t_off,
    const float* __restrict__ W, const float* __restrict__ b_ih,
    const float* __restrict__ b_hh, float* __restrict__ xg)
{
    const int tid = threadIdx.x;
    const int wv4 = (tid >> 6) * 4;
    const int lane = tid & 63;
    const int lane15 = lane & 15;
    const int quad = lane >> 4;
    const int blk = blockIdx.y;
    const int tbase = blockIdx.x * TG;

    DECLAI(0) DECLAI(1) DECLAI(2) DECLAI(3)
    GLOADA(0) GLOADA(1) GLOADA(2) GLOADA(3)

    f32x4 BIAS0, BIAS1, BIAS2, BIAS3;
    #define GBIAS(i) { int tl = wv4 + (i); int rowb = tl < 30 ? tl * 16 + quad * 4 : 476; \
        float4 bi = *(const float4*)(b_ih + rowb);                                        \
        if (tl < 20) { float4 bh = *(const float4*)(b_hh + rowb);                         \
            bi.x += bh.x; bi.y += bh.y; bi.z += bh.z; bi.w += bh.w; }                     \
        BIAS##i[0] = bi.x; BIAS##i[1] = bi.y; BIAS##i[2] = bi.z; BIAS##i[3] = bi.w; }
    GBIAS(0) GBIAS(1) GBIAS(2) GBIAS(3)
    #undef GBIAS

    const unsigned short* inb = in + (size_t)blk * in_blk_stride;
    float* xgb = xg + (size_t)blk * TC * 7680;

    for (int t = 0; t < TG; ++t) {
        const int tt = tbase + t;
        const unsigned short* ip =
            inb + ((size_t)(t_off + tt) * 16 + lane15) * K + quad * 8;
        half8 Bk0 = __builtin_bit_cast(half8, *(const uint4*)(ip));
        half8 Bk1 = __builtin_bit_cast(half8, *(const uint4*)(ip + 32));
        half8 Bk2 = Bk0, Bk3 = Bk0, Bk4 = Bk0;
        if (KT > 2) {
            Bk2 = __builtin_bit_cast(half8, *(const uint4*)(ip + 64));
            Bk3 = __builtin_bit_cast(half8, *(const uint4*)(ip + 96));
            Bk4 = __builtin_bit_cast(half8, *(const uint4*)(ip + 128));
        }
        f32x4 C0 = BIAS0, C1 = BIAS1, C2 = BIAS2, C3 = BIAS3;
        GMM(0, 0) GMM(1, 0) GMM(2, 0) GMM(3, 0)
        GMM(0, 1) GMM(1, 1) GMM(2, 1) GMM(3, 1)
        if (KT > 2) {
            GMM(0, 2) GMM(1, 2) GMM(2, 2) GMM(3, 2)
            GMM(0, 3) GMM(1, 3) GMM(2, 3) GMM(3, 3)
            GMM(0, 4) GMM(1, 4) GMM(2, 4) GMM(3, 4)
        }
        #define GSTORE(i) { int tl = wv4 + (i); if (tl < 30)                        \
            *(f32x4*)(xgb + (((size_t)tt * 30 + tl) * 16 + lane15) * 16 + quad * 4) \
                = C##i; }
        GSTORE(0) GSTORE(1) GSTORE(2) GSTORE(3)
        #undef GSTORE
    }
}

// ---------------------------------------------------------------------------
// K3: GRU scan chunk via MFMA. 4 blocks x 16 chains, 320 threads (5 waves).
// Wave w owns jr = {2w, 2w+1}; tiles r=jr, z=jr+10, n=jr+20 (gate-aligned).
// A-frags = W_hh rows (AGPR-resident, MFMA reads directly). B-frags = h from
// double-buffered LDS. h state fp32 in lane registers. ONE barrier/step.
// ---------------------------------------------------------------------------
#define DECLW(nm) half8 nm##_0, nm##_1, nm##_2, nm##_3, nm##_4;
#define LOADWH(nm, tb) { const float* wp = w_hh + (size_t)((tb) * 16 + lane15) * HH + quad * 8; \
    nm##_0 = load_wrow8(wp);       nm##_1 = load_wrow8(wp + 32);                                \
    nm##_2 = load_wrow8(wp + 64);  nm##_3 = load_wrow8(wp + 96);                                \
    nm##_4 = load_wrow8(wp + 128); }
#define SSTEPK(kt) { half8 Bk = __builtin_bit_cast(half8, hb[hbb + (kt) * 4]);   \
    Cr0 = MM16(Ar0_##kt, Bk, Cr0); Cr1 = MM16(Ar1_##kt, Bk, Cr1);               \
    Cz0 = MM16(Az0_##kt, Bk, Cz0); Cz1 = MM16(Az1_##kt, Bk, Cz1);               \
    Cn0 = MM16(An0_##kt, Bk, Cn0); Cn1 = MM16(An1_##kt, Bk, Cn1); }
#define GATEP(CR, CZ, CN, XR, XZ, XN, BH, HO, cmp, i) {   \
    float rg_ = fsigmoid(CR[i] + XR.cmp);                 \
    float ug_ = fsigmoid(CZ[i] + XZ.cmp);                 \
    float ng_ = ftanhf(XN.cmp + rg_ * (CN[i] + BH.cmp));  \
    HO.cmp = (1.f - ug_) * ng_ + ug_ * HO.cmp; }

template<bool WRITE_H>
__global__ void __launch_bounds__(320) __attribute__((amdgpu_waves_per_eu(2, 2)))
gru_scan_mfma(const float* __restrict__ xg,        // [blk][TC][30][16][16] f32
              const float* __restrict__ w_hh,      // [480][160] f32
              const float* __restrict__ b_hh,      // [480]
              float* __restrict__ h_state,         // [64][160] f32 carry
              unsigned short* __restrict__ h_out,  // [blk][TC][16][160] f16
              int first)
{
    const int blk = blockIdx.x;
    const int tid = threadIdx.x;
    const int wv = tid >> 6;
    const int lane = tid & 63;
    const int lane15 = lane & 15;
    const int quad = lane >> 4;
    const int jr0 = 2 * wv, jr1 = 2 * wv + 1;

    __shared__ unsigned short h_lds[2 * 16 * 168];  // double-buffered, pad 160->168

    DECLW(Ar0) DECLW(Ar1) DECLW(Az0) DECLW(Az1) DECLW(An0) DECLW(An1)
    LOADWH(Ar0, jr0) LOADWH(Ar1, jr1)
    LOADWH(Az0, 10 + jr0) LOADWH(Az1, 10 + jr1)
    LOADWH(An0, 20 + jr0) LOADWH(An1, 20 + jr1)

    float4 bhn0 = *(const float4*)(b_hh + 320 + jr0 * 16 + quad * 4);
    float4 bhn1 = *(const float4*)(b_hh + 320 + jr1 * 16 + quad * 4);

    // h state: this lane owns (chain=lane15, hid = 16*jr{0,1} + quad*4 + 0..3)
    float4 ho0 = {0.f, 0.f, 0.f, 0.f}, ho1 = {0.f, 0.f, 0.f, 0.f};
    float* hsp = h_state + (size_t)(blk * 16 + lane15) * HH;
    if (!first) {
        ho0 = *(const float4*)(hsp + jr0 * 16 + quad * 4);
        ho1 = *(const float4*)(hsp + jr1 * 16 + quad * 4);
    }
    u32* hl32 = (u32*)h_lds;
    hl32[lane15 * 84 + jr0 * 8 + quad * 2]     = packh2(ho0.x, ho0.y);
    hl32[lane15 * 84 + jr0 * 8 + quad * 2 + 1] = packh2(ho0.z, ho0.w);
    hl32[lane15 * 84 + jr1 * 8 + quad * 2]     = packh2(ho1.x, ho1.y);
    hl32[lane15 * 84 + jr1 * 8 + quad * 2 + 1] = packh2(ho1.z, ho1.w);

    const float4* xg4 = (const float4*)(xg + (size_t)blk * TC * 7680);
    const int xo_r0 = ((jr0)      * 16 + lane15) * 4 + quad;
    const int xo_r1 = ((jr1)      * 16 + lane15) * 4 + quad;
    const int xo_z0 = ((10 + jr0) * 16 + lane15) * 4 + quad;
    const int xo_z1 = ((10 + jr1) * 16 + lane15) * 4 + quad;
    const int xo_n0 = ((20 + jr0) * 16 + lane15) * 4 + quad;
    const int xo_n1 = ((20 + jr1) * 16 + lane15) * 4 + quad;

    u32* ho32 = (u32*)h_out + (size_t)blk * TC * 1280;
    const int hbb = lane15 * 21 + quad;  // uint4 index base in h buffer
    __syncthreads();

    for (int t = 0; t < TC; ++t) {
        const size_t toff = (size_t)t * 1920;
        float4 xr0 = xg4[toff + xo_r0];
        float4 xr1 = xg4[toff + xo_r1];
        float4 xz0 = xg4[toff + xo_z0];
        float4 xz1 = xg4[toff + xo_z1];
        float4 xn0 = xg4[toff + xo_n0];
        float4 xn1 = xg4[toff + xo_n1];

        const uint4* hb = (const uint4*)h_lds + (t & 1) * 336;
        f32x4 Cr0 = {0,0,0,0}, Cr1 = {0,0,0,0}, Cz0 = {0,0,0,0};
        f32x4 Cz1 = {0,0,0,0}, Cn0 = {0,0,0,0}, Cn1 = {0,0,0,0};
        SSTEPK(0) SSTEPK(1) SSTEPK(2) SSTEPK(3) SSTEPK(4)

        GATEP(Cr0, Cz0, Cn0, xr0, xz0, xn0, bhn0, ho0, x, 0)
        GATEP(Cr0, Cz0, Cn0, xr0, xz0, xn0, bhn0, ho0, y, 1)
        GATEP(Cr0, Cz0, Cn0, xr0, xz0, xn0, bhn0, ho0, z, 2)
        GATEP(Cr0, Cz0, Cn0, xr0, xz0, xn0, bhn0, ho0, w, 3)
        GATEP(Cr1, Cz1, Cn1, xr1, xz1, xn1, bhn1, ho1, x, 0)
        GATEP(Cr1, Cz1, Cn1, xr1, xz1, xn1, bhn1, ho1, y, 1)
        GATEP(Cr1, Cz1, Cn1, xr1, xz1, xn1, bhn1, ho1, z, 2)
        GATEP(Cr1, Cz1, Cn1, xr1, xz1, xn1, bhn1, ho1, w, 3)

        // write h_new into the other LDS buffer
        u32* hw = (u32*)h_lds + ((t + 1) & 1) * 1344;
        const u32 p00 = packh2(ho0.x, ho0.y), p01 = packh2(ho0.z, ho0.w);
        const u32 p10 = packh2(ho1.x, ho1.y), p11 = packh2(ho1.z, ho1.w);
        hw[lane15 * 84 + jr0 * 8 + quad * 2]     = p00;
        hw[lane15 * 84 + jr0 * 8 + quad * 2 + 1] = p01;
        hw[lane15 * 84 + jr1 * 8 + quad * 2]     = p10;
        hw[lane15 * 84 + jr1 * 8 + quad * 2 + 1] = p11;
        if (WRITE_H) {
            u32* hp = ho32 + (size_t)(t * 16 + lane15) * 80;
            hp[jr0 * 8 + quad * 2]     = p00;
            hp[jr0 * 8 + quad * 2 + 1] = p01;
            hp[jr1 * 8 + quad * 2]     = p10;
            hp[jr1 * 8 + quad * 2 + 1] = p11;
        }
        __syncthreads();
    }
    *(float4*)(hsp + jr0 * 16 + quad * 4) = ho0;
    *(float4*)(hsp + jr1 * 16 + quad * 4) = ho1;
}

// ---------------------------------------------------------------------------
// K4: MLP head from h2 final state.
// ---------------------------------------------------------------------------
__global__ __launch_bounds__(256) void head_kernel(
    const float* __restrict__ h_state,
    const float* __restrict__ hw1, const float* __restrict__ hb1,
    const float* __restrict__ hw2, const float* __restrict__ hb2,
    float* __restrict__ out)
{
    const int b = blockIdx.x;
    const int tid = threadIdx.x;
    __shared__ float hf[HH];
    __shared__ float q[80];
    if (tid < HH) hf[tid] = h_state[b * HH + tid];
    __syncthreads();
    if (tid < 80) {
        float a = hb1[tid];
        const float* wr = hw1 + (size_t)tid * HH;
        #pragma unroll 8
        for (int i = 0; i < HH; ++i) a = fmaf(wr[i], hf[i], a);
        q[tid] = gelu_exact(a);
    }
    __syncthreads();
    if (tid < 2) {
        float o = hb2[tid];
        const float* wr = hw2 + tid * 80;
        #pragma unroll 8
        for (int j = 0; j < 80; ++j) o = fmaf(wr[j], q[j], o);
        out[b * 2 + tid] = o;
    }
}

// ---------------------------------------------------------------------------
extern "C" void kernel_launch(void* const* d_in, const int* in_sizes, int n_in,
                              void* d_out, int out_size, void* d_ws, size_t ws_size,
                              hipStream_t stream)
{
    const float* x     = (const float*)d_in[0];
    const float* mix_w = (const float*)d_in[1];
    const float* bn_g  = (const float*)d_in[2];
    const float* bn_b  = (const float*)d_in[3];
    const float* bn_m  = (const float*)d_in[4];
    const float* bn_v  = (const float*)d_in[5];
    const float* w_ih1 = (const float*)d_in[6];
    const float* w_hh1 = (const float*)d_in[7];
    const float* b_ih1 = (const float*)d_in[8];
    const float* b_hh1 = (const float*)d_in[9];
    const float* w_ih2 = (const float*)d_in[10];
    const float* w_hh2 = (const float*)d_in[11];
    const float* b_ih2 = (const float*)d_in[12];
    const float* b_hh2 = (const float*)d_in[13];
    const float* hw1   = (const float*)d_in[14];
    const float* hb1   = (const float*)d_in[15];
    const float* hw2   = (const float*)d_in[16];
    const float* hb2   = (const float*)d_in[17];
    float* out = (float*)d_out;

    // ws (53.6 MB, proven-safe):
    //   z   f16 [4][T][16][64]      16.78 MB
    //   xg  f32 [4][TC][30][16][16] 31.46 MB (shared by layer1/layer2)
    //   h1c f16 [4][TC][16][160]     5.24 MB
    //   h1s,h2s f32 [64][160]        2 x 40 KB
    char* p = (char*)d_ws;
    u32* z_ws = (u32*)p;                  p += (size_t)BB * TT * 32 * 4;
    float* xg_ws = (float*)p;             p += (size_t)BB * TC * G3 * 4;
    unsigned short* h1c_ws = (unsigned short*)p;  p += (size_t)BB * TC * HH * 2;
    float* h1s = (float*)p;               p += (size_t)BB * HH * 4;
    float* h2s = (float*)p;

    conv_bn_gelu_kernel<<<dim3(16, BB), 256, 0, stream>>>(
        x, mix_w, bn_g, bn_b, bn_m, bn_v, z_ws);

    for (int c = 0; c < NC; ++c) {
        const int first = (c == 0) ? 1 : 0;
        xg_gemm_mfma<64, 2, 16><<<dim3(TC / 16, 4), 512, 0, stream>>>(
            (const unsigned short*)z_ws, (size_t)TT * 1024, c * TC,
            w_ih1, b_ih1, b_hh1, xg_ws);
        gru_scan_mfma<true><<<4, 320, 0, stream>>>(
            xg_ws, w_hh1, b_hh1, h1s, h1c_ws, first);
        xg_gemm_mfma<160, 5, 16><<<dim3(TC / 16, 4), 512, 0, stream>>>(
            h1c_ws, (size_t)TC * 2560, 0,
            w_ih2, b_ih2, b_hh2, xg_ws);
        gru_scan_mfma<false><<<4, 320, 0, stream>>>(
            xg_ws, w_hh2, b_hh2, h2s, nullptr, first);
    }

    head_kernel<<<BB, 256, 0, stream>>>(h2s, hw1, hb1, hw2, hb2, out);
}

// Round 8
// 6990.750 us; speedup vs baseline: 1.4701x; 1.4701x over previous
//
#include <hip/hip_runtime.h>
#include <cmath>

#define BB 64
#define TT 2048
#define FF 64
#define HH 160
#define G3 480
#define TC 256            // time-chunk length
#define NC (TT / TC)      // 8 chunks

typedef unsigned int u32;
typedef _Float16 half8 __attribute__((ext_vector_type(8)));
typedef _Float16 half2v __attribute__((ext_vector_type(2)));
typedef float f32x4 __attribute__((ext_vector_type(4)));

__device__ __forceinline__ unsigned short f2h(float v) {
    _Float16 h = (_Float16)v;
    return __builtin_bit_cast(unsigned short, h);
}
__device__ __forceinline__ u32 packh2(float a, float b) {
    return (u32)f2h(a) | ((u32)f2h(b) << 16);
}
__device__ __forceinline__ float h2lo(u32 p) {
    return (float)__builtin_bit_cast(half2v, p)[0];
}
__device__ __forceinline__ float h2hi(u32 p) {
    return (float)__builtin_bit_cast(half2v, p)[1];
}
__device__ __forceinline__ float fsigmoid(float v) { return 1.f / (1.f + __expf(-v)); }
__device__ __forceinline__ float ftanhf(float v) {
    float xc = fminf(fmaxf(v, -15.f), 15.f);
    float e = __expf(2.f * xc);
    return 1.f - 2.f / (e + 1.f);
}
__device__ __forceinline__ float gelu_exact(float v) {
    return 0.5f * v * (1.f + erff(v * 0.70710678118654752f));
}
// 8 consecutive f32 -> half8 (MFMA fragment order: element j = k-index j)
__device__ __forceinline__ half8 load_wrow8(const float* p) {
    const float4* q = (const float4*)p;
    float4 a = q[0], b = q[1];
    half8 r;
    r[0] = (_Float16)a.x; r[1] = (_Float16)a.y; r[2] = (_Float16)a.z; r[3] = (_Float16)a.w;
    r[4] = (_Float16)b.x; r[5] = (_Float16)b.y; r[6] = (_Float16)b.z; r[7] = (_Float16)b.w;
    return r;
}
#define MM16(A_, B_, C_) __builtin_amdgcn_mfma_f32_16x16x32_f16(A_, B_, C_, 0, 0, 0)

// ---------------------------------------------------------------------------
// K1: dilated conv + BN + exact GELU -> z f16 [B/16][T][16 chains][64] (u32 pairs)
// ---------------------------------------------------------------------------
__global__ __launch_bounds__(256) void conv_bn_gelu_kernel(
    const float* __restrict__ x, const float* __restrict__ mix_w,
    const float* __restrict__ bn_g, const float* __restrict__ bn_b,
    const float* __restrict__ bn_m, const float* __restrict__ bn_v,
    u32* __restrict__ z_out)
{
    __shared__ float ws_w[3][64][64];
    __shared__ float ws_x[132][64];
    const int b  = blockIdx.y;
    const int t0 = blockIdx.x * 128;
    const int tid = threadIdx.x;
    const int f  = tid & 63;
    const int rg = tid >> 6;

    for (int idx = tid; idx < 64 * 64 * 3; idx += 256) {
        int fo = idx / 192;
        int rem = idx - fo * 192;
        int fi = rem / 3;
        int k  = rem - fi * 3;
        ws_w[k][fi][fo] = mix_w[idx];
    }
    for (int row = rg; row < 132; row += 4) {
        int t = t0 - 2 + row;
        ws_x[row][f] = (t >= 0 && t < TT) ? x[((size_t)b * TT + t) * FF + f] : 0.f;
    }
    __syncthreads();

    const float scale = bn_g[f] * rsqrtf(bn_v[f] + 1e-5f);
    const float shift = bn_b[f] - bn_m[f] * scale;

    for (int ti = rg; ti < 128; ti += 4) {
        float acc = 0.f;
        #pragma unroll
        for (int k = 0; k < 3; ++k) {
            const float* xr = &ws_x[ti + 2 * k][0];
            #pragma unroll
            for (int fi = 0; fi < 64; ++fi)
                acc = fmaf(xr[fi], ws_w[k][fi][f], acc);
        }
        float y = fmaf(acc, scale, shift);
        float z = gelu_exact(y);
        float zp = __shfl_xor(z, 1);
        if ((f & 1) == 0)
            z_out[(((size_t)(b >> 4) * TT + (t0 + ti)) * 16 + (b & 15)) * 32 + (f >> 1)]
                = packh2(z, zp);
    }
}

// ---------------------------------------------------------------------------
// K2: xg GEMM via MFMA. D[n',chain] = W·in_t^T + bias, PACKED TO F16 pairs:
// xg[t][tile0..29][chain 0..15][n'/2 0..7] u32. grid (TC/TG, 4), block 512.
// ---------------------------------------------------------------------------
#define DECLAI(i) half8 A##i##_0, A##i##_1, A##i##_2, A##i##_3, A##i##_4;
#define GLOADA(i) { int tl = wv4 + (i); int rowc = tl < 30 ? tl * 16 + lane15 : 479; \
    const float* wp = W + (size_t)rowc * K + quad * 8;                               \
    A##i##_0 = load_wrow8(wp); A##i##_1 = load_wrow8(wp + 32);                       \
    if (KT > 2) { A##i##_2 = load_wrow8(wp + 64); A##i##_3 = load_wrow8(wp + 96);    \
                  A##i##_4 = load_wrow8(wp + 128); }                                 \
    else { A##i##_2 = A##i##_0; A##i##_3 = A##i##_0; A##i##_4 = A##i##_0; } }
#define GMM(i, kt) C##i = MM16(A##i##_##kt, Bk##kt, C##i);

template<int K, int KT, int TG>
__global__ __launch_bounds__(512) void xg_gemm_mfma(
    const unsigned short* __restrict__ in,  // f16 [blk][rows][16 chains][K]
    size_t in_blk_stride, int t_off,
    const float* __restrict__ W, const float* __restrict__ b_ih,
    const float* __restrict__ b_hh, u32* __restrict__ xg)
{
    const int tid = threadIdx.x;
    const int wv4 = (tid >> 6) * 4;
    const int lane = tid & 63;
    const int lane15 = lane & 15;
    const int quad = lane >> 4;
    const int blk = blockIdx.y;
    const int tbase = blockIdx.x * TG;

    DECLAI(0) DECLAI(1) DECLAI(2) DECLAI(3)
    GLOADA(0) GLOADA(1) GLOADA(2) GLOADA(3)

    f32x4 BIAS0, BIAS1, BIAS2, BIAS3;
    #define GBIAS(i) { int tl = wv4 + (i); int rowb = tl < 30 ? tl * 16 + quad * 4 : 476; \
        float4 bi = *(const float4*)(b_ih + rowb);                                        \
        if (tl < 20) { float4 bh = *(const float4*)(b_hh + rowb);                         \
            bi.x += bh.x; bi.y += bh.y; bi.z += bh.z; bi.w += bh.w; }                     \
        BIAS##i[0] = bi.x; BIAS##i[1] = bi.y; BIAS##i[2] = bi.z; BIAS##i[3] = bi.w; }
    GBIAS(0) GBIAS(1) GBIAS(2) GBIAS(3)
    #undef GBIAS

    const unsigned short* inb = in + (size_t)blk * in_blk_stride;
    u32* xgb = xg + (size_t)blk * TC * 3840;

    for (int t = 0; t < TG; ++t) {
        const int tt = tbase + t;
        const unsigned short* ip =
            inb + ((size_t)(t_off + tt) * 16 + lane15) * K + quad * 8;
        half8 Bk0 = __builtin_bit_cast(half8, *(const uint4*)(ip));
        half8 Bk1 = __builtin_bit_cast(half8, *(const uint4*)(ip + 32));
        half8 Bk2 = Bk0, Bk3 = Bk0, Bk4 = Bk0;
        if (KT > 2) {
            Bk2 = __builtin_bit_cast(half8, *(const uint4*)(ip + 64));
            Bk3 = __builtin_bit_cast(half8, *(const uint4*)(ip + 96));
            Bk4 = __builtin_bit_cast(half8, *(const uint4*)(ip + 128));
        }
        f32x4 C0 = BIAS0, C1 = BIAS1, C2 = BIAS2, C3 = BIAS3;
        GMM(0, 0) GMM(1, 0) GMM(2, 0) GMM(3, 0)
        GMM(0, 1) GMM(1, 1) GMM(2, 1) GMM(3, 1)
        if (KT > 2) {
            GMM(0, 2) GMM(1, 2) GMM(2, 2) GMM(3, 2)
            GMM(0, 3) GMM(1, 3) GMM(2, 3) GMM(3, 3)
            GMM(0, 4) GMM(1, 4) GMM(2, 4) GMM(3, 4)
        }
        #define GSTORE(i) { int tl = wv4 + (i); if (tl < 30) {                      \
            u32 q0 = packh2(C##i[0], C##i[1]);                                      \
            u32 q1 = packh2(C##i[2], C##i[3]);                                      \
            *(uint2*)(xgb + (((size_t)tt * 30 + tl) * 16 + lane15) * 8 + quad * 2)  \
                = (uint2){q0, q1}; } }
        GSTORE(0) GSTORE(1) GSTORE(2) GSTORE(3)
        #undef GSTORE
    }
}

// ---------------------------------------------------------------------------
// K3: GRU scan chunk via MFMA. 4 blocks x 16 chains, 640 threads (10 waves).
// Wave w owns hidden slice w: tiles r=w, z=w+10, n=w+20 -> 15 A-frags
// (60 VGPR) + 3 C-frags. Gate-aligned: lane owns chain=lane15,
// hid=w*16+quad*4..+3. xg f16 prefetched one step ahead. One barrier/step.
// ---------------------------------------------------------------------------
#define DECLW(nm) half8 nm##0, nm##1, nm##2, nm##3, nm##4;
#define LOADWH(nm, tb) { const float* wp = w_hh + (size_t)((tb) * 16 + lane15) * HH + quad * 8; \
    nm##0 = load_wrow8(wp);       nm##1 = load_wrow8(wp + 32);                                  \
    nm##2 = load_wrow8(wp + 64);  nm##3 = load_wrow8(wp + 96);                                  \
    nm##4 = load_wrow8(wp + 128); }
#define GATE1(i, CRi, CZi, CNi, XRv, XZv, XNv, BHv, HOc) {  \
    float rr = fsigmoid(CRi + XRv);                         \
    float uu = fsigmoid(CZi + XZv);                         \
    float nn = ftanhf(XNv + rr * (CNi + BHv));              \
    HOc = (1.f - uu) * nn + uu * HOc; }

template<bool WRITE_H>
__global__ __launch_bounds__(640) void gru_scan_mfma(
    const u32* __restrict__ xg,          // f16 pairs [blk][TC][30][16][8] u32
    const float* __restrict__ w_hh,      // [480][160] f32
    const float* __restrict__ b_hh,      // [480]
    float* __restrict__ h_state,         // [64][160] f32 carry
    unsigned short* __restrict__ h_out,  // [blk][TC][16][160] f16
    int first)
{
    const int blk = blockIdx.x;
    const int tid = threadIdx.x;
    const int wv = tid >> 6;       // 0..9 = hidden slice
    const int lane = tid & 63;
    const int lane15 = lane & 15;
    const int quad = lane >> 4;

    __shared__ unsigned short h_lds[2 * 16 * 168];  // double-buffered, pad 160->168

    DECLW(Ar) DECLW(Az) DECLW(An)
    LOADWH(Ar, wv) LOADWH(Az, 10 + wv) LOADWH(An, 20 + wv)

    const float4 bhn = *(const float4*)(b_hh + 320 + wv * 16 + quad * 4);

    // h state: this lane owns (chain=lane15, hid = wv*16 + quad*4 + 0..3)
    float4 ho = {0.f, 0.f, 0.f, 0.f};
    float* hsp = h_state + (size_t)(blk * 16 + lane15) * HH;
    if (!first) ho = *(const float4*)(hsp + wv * 16 + quad * 4);

    u32* hl32 = (u32*)h_lds;
    const int hwi = lane15 * 84 + wv * 8 + quad * 2;
    hl32[hwi]     = packh2(ho.x, ho.y);
    hl32[hwi + 1] = packh2(ho.z, ho.w);

    const u32* xgb = xg + (size_t)blk * TC * 3840;
    const int xo_r = ((wv)      * 16 + lane15) * 8 + quad * 2;
    const int xo_z = ((10 + wv) * 16 + lane15) * 8 + quad * 2;
    const int xo_n = ((20 + wv) * 16 + lane15) * 8 + quad * 2;

    uint2 xr = *(const uint2*)(xgb + xo_r);
    uint2 xz = *(const uint2*)(xgb + xo_z);
    uint2 xn = *(const uint2*)(xgb + xo_n);

    u32* ho32 = (u32*)h_out + (size_t)blk * TC * 1280;
    const int hbb = lane15 * 21 + quad;  // uint4 read base in h buffer
    __syncthreads();

    for (int t = 0; t < TC; ++t) {
        // read h(t) fragments from current LDS buffer
        const uint4* hb = (const uint4*)h_lds + (t & 1) * 336;
        uint4 b0 = hb[hbb];
        uint4 b1 = hb[hbb + 4];
        uint4 b2 = hb[hbb + 8];
        uint4 b3 = hb[hbb + 12];
        uint4 b4 = hb[hbb + 16];

        // prefetch xg(t+1)
        const int tn = (t + 1 < TC) ? t + 1 : t;
        const u32* xgt = xgb + (size_t)tn * 3840;
        uint2 xr_n = *(const uint2*)(xgt + xo_r);
        uint2 xz_n = *(const uint2*)(xgt + xo_z);
        uint2 xn_n = *(const uint2*)(xgt + xo_n);

        f32x4 Cr = {0.f, 0.f, 0.f, 0.f};
        f32x4 Cz = {0.f, 0.f, 0.f, 0.f};
        f32x4 Cn = {0.f, 0.f, 0.f, 0.f};
        half8 B0 = __builtin_bit_cast(half8, b0);
        Cr = MM16(Ar0, B0, Cr); Cz = MM16(Az0, B0, Cz); Cn = MM16(An0, B0, Cn);
        half8 B1 = __builtin_bit_cast(half8, b1);
        Cr = MM16(Ar1, B1, Cr); Cz = MM16(Az1, B1, Cz); Cn = MM16(An1, B1, Cn);
        half8 B2 = __builtin_bit_cast(half8, b2);
        Cr = MM16(Ar2, B2, Cr); Cz = MM16(Az2, B2, Cz); Cn = MM16(An2, B2, Cn);
        half8 B3 = __builtin_bit_cast(half8, b3);
        Cr = MM16(Ar3, B3, Cr); Cz = MM16(Az3, B3, Cz); Cn = MM16(An3, B3, Cn);
        half8 B4 = __builtin_bit_cast(half8, b4);
        Cr = MM16(Ar4, B4, Cr); Cz = MM16(Az4, B4, Cz); Cn = MM16(An4, B4, Cn);

        GATE1(0, Cr[0], Cz[0], Cn[0], h2lo(xr.x), h2lo(xz.x), h2lo(xn.x), bhn.x, ho.x)
        GATE1(1, Cr[1], Cz[1], Cn[1], h2hi(xr.x), h2hi(xz.x), h2hi(xn.x), bhn.y, ho.y)
        GATE1(2, Cr[2], Cz[2], Cn[2], h2lo(xr.y), h2lo(xz.y), h2lo(xn.y), bhn.z, ho.z)
        GATE1(3, Cr[3], Cz[3], Cn[3], h2hi(xr.y), h2hi(xz.y), h2hi(xn.y), bhn.w, ho.w)

        const u32 p0 = packh2(ho.x, ho.y);
        const u32 p1 = packh2(ho.z, ho.w);
        u32* hw = hl32 + ((t + 1) & 1) * 1344;
        hw[hwi]     = p0;
        hw[hwi + 1] = p1;
        if (WRITE_H) {
            u32* hp = ho32 + (size_t)(t * 16 + lane15) * 80;
            hp[wv * 8 + quad * 2]     = p0;
            hp[wv * 8 + quad * 2 + 1] = p1;
        }
        __syncthreads();
        xr = xr_n; xz = xz_n; xn = xn_n;
    }
    *(float4*)(hsp + wv * 16 + quad * 4) = ho;
}

// ---------------------------------------------------------------------------
// K4: MLP head from h2 final state.
// ---------------------------------------------------------------------------
__global__ __launch_bounds__(256) void head_kernel(
    const float* __restrict__ h_state,
    const float* __restrict__ hw1, const float* __restrict__ hb1,
    const float* __restrict__ hw2, const float* __restrict__ hb2,
    float* __restrict__ out)
{
    const int b = blockIdx.x;
    const int tid = threadIdx.x;
    __shared__ float hf[HH];
    __shared__ float q[80];
    if (tid < HH) hf[tid] = h_state[b * HH + tid];
    __syncthreads();
    if (tid < 80) {
        float a = hb1[tid];
        const float* wr = hw1 + (size_t)tid * HH;
        #pragma unroll 8
        for (int i = 0; i < HH; ++i) a = fmaf(wr[i], hf[i], a);
        q[tid] = gelu_exact(a);
    }
    __syncthreads();
    if (tid < 2) {
        float o = hb2[tid];
        const float* wr = hw2 + tid * 80;
        #pragma unroll 8
        for (int j = 0; j < 80; ++j) o = fmaf(wr[j], q[j], o);
        out[b * 2 + tid] = o;
    }
}

// ---------------------------------------------------------------------------
extern "C" void kernel_launch(void* const* d_in, const int* in_sizes, int n_in,
                              void* d_out, int out_size, void* d_ws, size_t ws_size,
                              hipStream_t stream)
{
    const float* x     = (const float*)d_in[0];
    const float* mix_w = (const float*)d_in[1];
    const float* bn_g  = (const float*)d_in[2];
    const float* bn_b  = (const float*)d_in[3];
    const float* bn_m  = (const float*)d_in[4];
    const float* bn_v  = (const float*)d_in[5];
    const float* w_ih1 = (const float*)d_in[6];
    const float* w_hh1 = (const float*)d_in[7];
    const float* b_ih1 = (const float*)d_in[8];
    const float* b_hh1 = (const float*)d_in[9];
    const float* w_ih2 = (const float*)d_in[10];
    const float* w_hh2 = (const float*)d_in[11];
    const float* b_ih2 = (const float*)d_in[12];
    const float* b_hh2 = (const float*)d_in[13];
    const float* hw1   = (const float*)d_in[14];
    const float* hb1   = (const float*)d_in[15];
    const float* hw2   = (const float*)d_in[16];
    const float* hb2   = (const float*)d_in[17];
    float* out = (float*)d_out;

    // ws (~37.8 MB):
    //   z   f16 [4][T][16][64]          16.78 MB
    //   xg  f16 [4][TC][30][16][16]     15.73 MB (shared by layer1/layer2)
    //   h1c f16 [4][TC][16][160]         5.24 MB
    //   h1s,h2s f32 [64][160]            2 x 40 KB
    char* p = (char*)d_ws;
    u32* z_ws = (u32*)p;                  p += (size_t)BB * TT * 32 * 4;
    u32* xg_ws = (u32*)p;                 p += (size_t)4 * TC * 3840 * 4;
    unsigned short* h1c_ws = (unsigned short*)p;  p += (size_t)BB * TC * HH * 2;
    float* h1s = (float*)p;               p += (size_t)BB * HH * 4;
    float* h2s = (float*)p;

    conv_bn_gelu_kernel<<<dim3(16, BB), 256, 0, stream>>>(
        x, mix_w, bn_g, bn_b, bn_m, bn_v, z_ws);

    for (int c = 0; c < NC; ++c) {
        const int first = (c == 0) ? 1 : 0;
        xg_gemm_mfma<64, 2, 16><<<dim3(TC / 16, 4), 512, 0, stream>>>(
            (const unsigned short*)z_ws, (size_t)TT * 1024, c * TC,
            w_ih1, b_ih1, b_hh1, xg_ws);
        gru_scan_mfma<true><<<4, 640, 0, stream>>>(
            xg_ws, w_hh1, b_hh1, h1s, h1c_ws, first);
        xg_gemm_mfma<160, 5, 16><<<dim3(TC / 16, 4), 512, 0, stream>>>(
            h1c_ws, (size_t)TC * 2560, 0,
            w_ih2, b_ih2, b_hh2, xg_ws);
        gru_scan_mfma<false><<<4, 640, 0, stream>>>(
            xg_ws, w_hh2, b_hh2, h2s, nullptr, first);
    }

    head_kernel<<<BB, 256, 0, stream>>>(h2s, hw1, hb1, hw2, hb2, out);
}

// Round 9
// 6877.671 us; speedup vs baseline: 1.4942x; 1.0164x over previous
//
#include <hip/hip_runtime.h>
#include <cmath>

#define BB 64
#define TT 2048
#define FF 64
#define HH 160
#define G3 480
#define TC 256            // time-chunk length
#define NC (TT / TC)      // 8 chunks

typedef unsigned int u32;
typedef _Float16 half8 __attribute__((ext_vector_type(8)));
typedef _Float16 half2v __attribute__((ext_vector_type(2)));
typedef float f32x4 __attribute__((ext_vector_type(4)));

__device__ __forceinline__ unsigned short f2h(float v) {
    _Float16 h = (_Float16)v;
    return __builtin_bit_cast(unsigned short, h);
}
__device__ __forceinline__ u32 packh2(float a, float b) {
    return (u32)f2h(a) | ((u32)f2h(b) << 16);
}
__device__ __forceinline__ float h2lo(u32 p) {
    return (float)__builtin_bit_cast(half2v, p)[0];
}
__device__ __forceinline__ float h2hi(u32 p) {
    return (float)__builtin_bit_cast(half2v, p)[1];
}
__device__ __forceinline__ float fsigmoid(float v) { return 1.f / (1.f + __expf(-v)); }
__device__ __forceinline__ float ftanhf(float v) {
    float xc = fminf(fmaxf(v, -15.f), 15.f);
    float e = __expf(2.f * xc);
    return 1.f - 2.f / (e + 1.f);
}
__device__ __forceinline__ float gelu_exact(float v) {
    return 0.5f * v * (1.f + erff(v * 0.70710678118654752f));
}
// barrier that waits only on LDS ops (NOT vmcnt) — keeps global loads/stores
// in flight across steps. Safe: h is double-buffered; xg/h_out are per-thread.
__device__ __forceinline__ void barrier_lgkm() {
    asm volatile("s_waitcnt lgkmcnt(0)\ns_barrier" ::: "memory");
}
// 8 consecutive f32 -> half8 (MFMA fragment order: element j = k-index j)
__device__ __forceinline__ half8 load_wrow8(const float* p) {
    const float4* q = (const float4*)p;
    float4 a = q[0], b = q[1];
    half8 r;
    r[0] = (_Float16)a.x; r[1] = (_Float16)a.y; r[2] = (_Float16)a.z; r[3] = (_Float16)a.w;
    r[4] = (_Float16)b.x; r[5] = (_Float16)b.y; r[6] = (_Float16)b.z; r[7] = (_Float16)b.w;
    return r;
}
#define MM16(A_, B_, C_) __builtin_amdgcn_mfma_f32_16x16x32_f16(A_, B_, C_, 0, 0, 0)

// ---------------------------------------------------------------------------
// K1: dilated conv + BN + exact GELU -> z f16 [B/16][T][16 chains][64] (u32 pairs)
// ---------------------------------------------------------------------------
__global__ __launch_bounds__(256) void conv_bn_gelu_kernel(
    const float* __restrict__ x, const float* __restrict__ mix_w,
    const float* __restrict__ bn_g, const float* __restrict__ bn_b,
    const float* __restrict__ bn_m, const float* __restrict__ bn_v,
    u32* __restrict__ z_out)
{
    __shared__ float ws_w[3][64][64];
    __shared__ float ws_x[132][64];
    const int b  = blockIdx.y;
    const int t0 = blockIdx.x * 128;
    const int tid = threadIdx.x;
    const int f  = tid & 63;
    const int rg = tid >> 6;

    for (int idx = tid; idx < 64 * 64 * 3; idx += 256) {
        int fo = idx / 192;
        int rem = idx - fo * 192;
        int fi = rem / 3;
        int k  = rem - fi * 3;
        ws_w[k][fi][fo] = mix_w[idx];
    }
    for (int row = rg; row < 132; row += 4) {
        int t = t0 - 2 + row;
        ws_x[row][f] = (t >= 0 && t < TT) ? x[((size_t)b * TT + t) * FF + f] : 0.f;
    }
    __syncthreads();

    const float scale = bn_g[f] * rsqrtf(bn_v[f] + 1e-5f);
    const float shift = bn_b[f] - bn_m[f] * scale;

    for (int ti = rg; ti < 128; ti += 4) {
        float acc = 0.f;
        #pragma unroll
        for (int k = 0; k < 3; ++k) {
            const float* xr = &ws_x[ti + 2 * k][0];
            #pragma unroll
            for (int fi = 0; fi < 64; ++fi)
                acc = fmaf(xr[fi], ws_w[k][fi][f], acc);
        }
        float y = fmaf(acc, scale, shift);
        float z = gelu_exact(y);
        float zp = __shfl_xor(z, 1);
        if ((f & 1) == 0)
            z_out[(((size_t)(b >> 4) * TT + (t0 + ti)) * 16 + (b & 15)) * 32 + (f >> 1)]
                = packh2(z, zp);
    }
}

// ---------------------------------------------------------------------------
// K2: xg GEMM via MFMA. D[n',chain] = W·in_t^T + bias, PACKED TO F16 pairs:
// xg[t][tile0..29][chain 0..15][n'/2 0..7] u32. grid (TC/TG, 4), block 512.
// ---------------------------------------------------------------------------
#define DECLAI(i) half8 A##i##_0, A##i##_1, A##i##_2, A##i##_3, A##i##_4;
#define GLOADA(i) { int tl = wv4 + (i); int rowc = tl < 30 ? tl * 16 + lane15 : 479; \
    const float* wp = W + (size_t)rowc * K + quad * 8;                               \
    A##i##_0 = load_wrow8(wp); A##i##_1 = load_wrow8(wp + 32);                       \
    if (KT > 2) { A##i##_2 = load_wrow8(wp + 64); A##i##_3 = load_wrow8(wp + 96);    \
                  A##i##_4 = load_wrow8(wp + 128); }                                 \
    else { A##i##_2 = A##i##_0; A##i##_3 = A##i##_0; A##i##_4 = A##i##_0; } }
#define GMM(i, kt) C##i = MM16(A##i##_##kt, Bk##kt, C##i);

template<int K, int KT, int TG>
__global__ __launch_bounds__(512) void xg_gemm_mfma(
    const unsigned short* __restrict__ in,  // f16 [blk][rows][16 chains][K]
    size_t in_blk_stride, int t_off,
    const float* __restrict__ W, const float* __restrict__ b_ih,
    const float* __restrict__ b_hh, u32* __restrict__ xg)
{
    const int tid = threadIdx.x;
    const int wv4 = (tid >> 6) * 4;
    const int lane = tid & 63;
    const int lane15 = lane & 15;
    const int quad = lane >> 4;
    const int blk = blockIdx.y;
    const int tbase = blockIdx.x * TG;

    DECLAI(0) DECLAI(1) DECLAI(2) DECLAI(3)
    GLOADA(0) GLOADA(1) GLOADA(2) GLOADA(3)

    f32x4 BIAS0, BIAS1, BIAS2, BIAS3;
    #define GBIAS(i) { int tl = wv4 + (i); int rowb = tl < 30 ? tl * 16 + quad * 4 : 476; \
        float4 bi = *(const float4*)(b_ih + rowb);                                        \
        if (tl < 20) { float4 bh = *(const float4*)(b_hh + rowb);                         \
            bi.x += bh.x; bi.y += bh.y; bi.z += bh.z; bi.w += bh.w; }                     \
        BIAS##i[0] = bi.x; BIAS##i[1] = bi.y; BIAS##i[2] = bi.z; BIAS##i[3] = bi.w; }
    GBIAS(0) GBIAS(1) GBIAS(2) GBIAS(3)
    #undef GBIAS

    const unsigned short* inb = in + (size_t)blk * in_blk_stride;
    u32* xgb = xg + (size_t)blk * TC * 3840;

    for (int t = 0; t < TG; ++t) {
        const int tt = tbase + t;
        const unsigned short* ip =
            inb + ((size_t)(t_off + tt) * 16 + lane15) * K + quad * 8;
        half8 Bk0 = __builtin_bit_cast(half8, *(const uint4*)(ip));
        half8 Bk1 = __builtin_bit_cast(half8, *(const uint4*)(ip + 32));
        half8 Bk2 = Bk0, Bk3 = Bk0, Bk4 = Bk0;
        if (KT > 2) {
            Bk2 = __builtin_bit_cast(half8, *(const uint4*)(ip + 64));
            Bk3 = __builtin_bit_cast(half8, *(const uint4*)(ip + 96));
            Bk4 = __builtin_bit_cast(half8, *(const uint4*)(ip + 128));
        }
        f32x4 C0 = BIAS0, C1 = BIAS1, C2 = BIAS2, C3 = BIAS3;
        GMM(0, 0) GMM(1, 0) GMM(2, 0) GMM(3, 0)
        GMM(0, 1) GMM(1, 1) GMM(2, 1) GMM(3, 1)
        if (KT > 2) {
            GMM(0, 2) GMM(1, 2) GMM(2, 2) GMM(3, 2)
            GMM(0, 3) GMM(1, 3) GMM(2, 3) GMM(3, 3)
            GMM(0, 4) GMM(1, 4) GMM(2, 4) GMM(3, 4)
        }
        #define GSTORE(i) { int tl = wv4 + (i); if (tl < 30) {                      \
            u32 q0 = packh2(C##i[0], C##i[1]);                                      \
            u32 q1 = packh2(C##i[2], C##i[3]);                                      \
            *(uint2*)(xgb + (((size_t)tt * 30 + tl) * 16 + lane15) * 8 + quad * 2)  \
                = (uint2){q0, q1}; } }
        GSTORE(0) GSTORE(1) GSTORE(2) GSTORE(3)
        #undef GSTORE
    }
}

// ---------------------------------------------------------------------------
// K3: GRU scan chunk via MFMA. 4 blocks x 16 chains, 640 threads (10 waves).
// Wave w owns tiles r=w, z=w+10, n=w+20 (15 A-frags, AGPR-resident).
// h double-buffered in LDS, layout [kt][quad][chain] uint4 -> the per-kt read
// address is kt*64+lane: lane-linear, conflict-free b128.
// In-loop barrier waits lgkmcnt ONLY (no vmcnt drain of xg/h_out traffic).
// ---------------------------------------------------------------------------
#define DECLW(nm) half8 nm##0, nm##1, nm##2, nm##3, nm##4;
#define LOADWH(nm, tb) { const float* wp = w_hh + (size_t)((tb) * 16 + lane15) * HH + quad * 8; \
    nm##0 = load_wrow8(wp);       nm##1 = load_wrow8(wp + 32);                                  \
    nm##2 = load_wrow8(wp + 64);  nm##3 = load_wrow8(wp + 96);                                  \
    nm##4 = load_wrow8(wp + 128); }
#define GATE1(CRi, CZi, CNi, XRv, XZv, XNv, BHv, HOc) {     \
    float rr = fsigmoid(CRi + XRv);                         \
    float uu = fsigmoid(CZi + XZv);                         \
    float nn = ftanhf(XNv + rr * (CNi + BHv));              \
    HOc = (1.f - uu) * nn + uu * HOc; }

template<bool WRITE_H>
__global__ __launch_bounds__(640) void gru_scan_mfma(
    const u32* __restrict__ xg,          // f16 pairs [blk][TC][30][16][8] u32
    const float* __restrict__ w_hh,      // [480][160] f32
    const float* __restrict__ b_hh,      // [480]
    float* __restrict__ h_state,         // [64][160] f32 carry
    unsigned short* __restrict__ h_out,  // [blk][TC][16][160] f16
    int first)
{
    const int blk = blockIdx.x;
    const int tid = threadIdx.x;
    const int wv = tid >> 6;       // 0..9 = hidden slice
    const int lane = tid & 63;
    const int lane15 = lane & 15;
    const int quad = lane >> 4;

    // [2 buf][kt 0..4][quad 0..3][chain 0..15] uint4
    __shared__ uint4 h_lds[2 * 320];

    DECLW(Ar) DECLW(Az) DECLW(An)
    LOADWH(Ar, wv) LOADWH(Az, 10 + wv) LOADWH(An, 20 + wv)

    const float4 bhn = *(const float4*)(b_hh + 320 + wv * 16 + quad * 4);

    // h state: this lane owns (chain=lane15, hid = wv*16 + quad*4 + 0..3)
    float4 ho = {0.f, 0.f, 0.f, 0.f};
    float* hsp = h_state + (size_t)(blk * 16 + lane15) * HH;
    if (!first) ho = *(const float4*)(hsp + wv * 16 + quad * 4);

    // write index for this lane's 2 u32 of h (see mapping derivation):
    // k-base = wv*16+quad*4 -> kt=wv>>1, q=(wv&1)*2+(quad>>1), u32off=(quad&1)*2
    const int hwidx = (((wv >> 1) * 4 + ((wv & 1) * 2 + (quad >> 1))) * 16 + lane15) * 4
                    + (quad & 1) * 2;
    u32* hl32 = (u32*)h_lds;
    hl32[hwidx]     = packh2(ho.x, ho.y);
    hl32[hwidx + 1] = packh2(ho.z, ho.w);

    const u32* xgb = xg + (size_t)blk * TC * 3840;
    const int xo_r = ((wv)      * 16 + lane15) * 8 + quad * 2;
    const int xo_z = ((10 + wv) * 16 + lane15) * 8 + quad * 2;
    const int xo_n = ((20 + wv) * 16 + lane15) * 8 + quad * 2;

    uint2 xr = *(const uint2*)(xgb + xo_r);
    uint2 xz = *(const uint2*)(xgb + xo_z);
    uint2 xn = *(const uint2*)(xgb + xo_n);

    u32* ho32 = (u32*)h_out + (size_t)blk * TC * 1280;
    __syncthreads();

    for (int t = 0; t < TC; ++t) {
        // h(t) B-frags: lane-linear, conflict-free
        const uint4* hb = h_lds + (t & 1) * 320;
        uint4 b0 = hb[lane];
        uint4 b1 = hb[64 + lane];
        uint4 b2 = hb[128 + lane];
        uint4 b3 = hb[192 + lane];
        uint4 b4 = hb[256 + lane];

        // prefetch xg(t+1) — stays in flight across the lgkm-only barrier
        const int tn = (t + 1 < TC) ? t + 1 : t;
        const u32* xgt = xgb + (size_t)tn * 3840;
        uint2 xr_n = *(const uint2*)(xgt + xo_r);
        uint2 xz_n = *(const uint2*)(xgt + xo_z);
        uint2 xn_n = *(const uint2*)(xgt + xo_n);

        f32x4 Cr = {0.f, 0.f, 0.f, 0.f};
        f32x4 Cz = {0.f, 0.f, 0.f, 0.f};
        f32x4 Cn = {0.f, 0.f, 0.f, 0.f};
        half8 B0 = __builtin_bit_cast(half8, b0);
        Cr = MM16(Ar0, B0, Cr); Cz = MM16(Az0, B0, Cz); Cn = MM16(An0, B0, Cn);
        half8 B1 = __builtin_bit_cast(half8, b1);
        Cr = MM16(Ar1, B1, Cr); Cz = MM16(Az1, B1, Cz); Cn = MM16(An1, B1, Cn);
        half8 B2 = __builtin_bit_cast(half8, b2);
        Cr = MM16(Ar2, B2, Cr); Cz = MM16(Az2, B2, Cz); Cn = MM16(An2, B2, Cn);
        half8 B3 = __builtin_bit_cast(half8, b3);
        Cr = MM16(Ar3, B3, Cr); Cz = MM16(Az3, B3, Cz); Cn = MM16(An3, B3, Cn);
        half8 B4 = __builtin_bit_cast(half8, b4);
        Cr = MM16(Ar4, B4, Cr); Cz = MM16(Az4, B4, Cz); Cn = MM16(An4, B4, Cn);

        GATE1(Cr[0], Cz[0], Cn[0], h2lo(xr.x), h2lo(xz.x), h2lo(xn.x), bhn.x, ho.x)
        GATE1(Cr[1], Cz[1], Cn[1], h2hi(xr.x), h2hi(xz.x), h2hi(xn.x), bhn.y, ho.y)
        GATE1(Cr[2], Cz[2], Cn[2], h2lo(xr.y), h2lo(xz.y), h2lo(xn.y), bhn.z, ho.z)
        GATE1(Cr[3], Cz[3], Cn[3], h2hi(xr.y), h2hi(xz.y), h2hi(xn.y), bhn.w, ho.w)

        const u32 p0 = packh2(ho.x, ho.y);
        const u32 p1 = packh2(ho.z, ho.w);
        u32* hw = hl32 + ((t + 1) & 1) * 1280;
        hw[hwidx]     = p0;
        hw[hwidx + 1] = p1;
        if (WRITE_H) {
            u32* hp = ho32 + (size_t)(t * 16 + lane15) * 80;
            hp[wv * 8 + quad * 2]     = p0;
            hp[wv * 8 + quad * 2 + 1] = p1;
        }
        barrier_lgkm();
        xr = xr_n; xz = xz_n; xn = xn_n;
    }
    *(float4*)(hsp + wv * 16 + quad * 4) = ho;
}

// ---------------------------------------------------------------------------
// K4: MLP head from h2 final state.
// ---------------------------------------------------------------------------
__global__ __launch_bounds__(256) void head_kernel(
    const float* __restrict__ h_state,
    const float* __restrict__ hw1, const float* __restrict__ hb1,
    const float* __restrict__ hw2, const float* __restrict__ hb2,
    float* __restrict__ out)
{
    const int b = blockIdx.x;
    const int tid = threadIdx.x;
    __shared__ float hf[HH];
    __shared__ float q[80];
    if (tid < HH) hf[tid] = h_state[b * HH + tid];
    __syncthreads();
    if (tid < 80) {
        float a = hb1[tid];
        const float* wr = hw1 + (size_t)tid * HH;
        #pragma unroll 8
        for (int i = 0; i < HH; ++i) a = fmaf(wr[i], hf[i], a);
        q[tid] = gelu_exact(a);
    }
    __syncthreads();
    if (tid < 2) {
        float o = hb2[tid];
        const float* wr = hw2 + tid * 80;
        #pragma unroll 8
        for (int j = 0; j < 80; ++j) o = fmaf(wr[j], q[j], o);
        out[b * 2 + tid] = o;
    }
}

// ---------------------------------------------------------------------------
extern "C" void kernel_launch(void* const* d_in, const int* in_sizes, int n_in,
                              void* d_out, int out_size, void* d_ws, size_t ws_size,
                              hipStream_t stream)
{
    const float* x     = (const float*)d_in[0];
    const float* mix_w = (const float*)d_in[1];
    const float* bn_g  = (const float*)d_in[2];
    const float* bn_b  = (const float*)d_in[3];
    const float* bn_m  = (const float*)d_in[4];
    const float* bn_v  = (const float*)d_in[5];
    const float* w_ih1 = (const float*)d_in[6];
    const float* w_hh1 = (const float*)d_in[7];
    const float* b_ih1 = (const float*)d_in[8];
    const float* b_hh1 = (const float*)d_in[9];
    const float* w_ih2 = (const float*)d_in[10];
    const float* w_hh2 = (const float*)d_in[11];
    const float* b_ih2 = (const float*)d_in[12];
    const float* b_hh2 = (const float*)d_in[13];
    const float* hw1   = (const float*)d_in[14];
    const float* hb1   = (const float*)d_in[15];
    const float* hw2   = (const float*)d_in[16];
    const float* hb2   = (const float*)d_in[17];
    float* out = (float*)d_out;

    // ws (~37.8 MB):
    //   z   f16 [4][T][16][64]          16.78 MB
    //   xg  f16 [4][TC][30][16][16]     15.73 MB (shared by layer1/layer2)
    //   h1c f16 [4][TC][16][160]         5.24 MB
    //   h1s,h2s f32 [64][160]            2 x 40 KB
    char* p = (char*)d_ws;
    u32* z_ws = (u32*)p;                  p += (size_t)BB * TT * 32 * 4;
    u32* xg_ws = (u32*)p;                 p += (size_t)4 * TC * 3840 * 4;
    unsigned short* h1c_ws = (unsigned short*)p;  p += (size_t)BB * TC * HH * 2;
    float* h1s = (float*)p;               p += (size_t)BB * HH * 4;
    float* h2s = (float*)p;

    conv_bn_gelu_kernel<<<dim3(16, BB), 256, 0, stream>>>(
        x, mix_w, bn_g, bn_b, bn_m, bn_v, z_ws);

    for (int c = 0; c < NC; ++c) {
        const int first = (c == 0) ? 1 : 0;
        xg_gemm_mfma<64, 2, 4><<<dim3(TC / 4, 4), 512, 0, stream>>>(
            (const unsigned short*)z_ws, (size_t)TT * 1024, c * TC,
            w_ih1, b_ih1, b_hh1, xg_ws);
        gru_scan_mfma<true><<<4, 640, 0, stream>>>(
            xg_ws, w_hh1, b_hh1, h1s, h1c_ws, first);
        xg_gemm_mfma<160, 5, 4><<<dim3(TC / 4, 4), 512, 0, stream>>>(
            h1c_ws, (size_t)TC * 2560, 0,
            w_ih2, b_ih2, b_hh2, xg_ws);
        gru_scan_mfma<false><<<4, 640, 0, stream>>>(
            xg_ws, w_hh2, b_hh2, h2s, nullptr, first);
    }

    head_kernel<<<BB, 256, 0, stream>>>(h2s, hw1, hb1, hw2, hb2, out);
}

// Round 10
// 3918.341 us; speedup vs baseline: 2.6228x; 1.7553x over previous
//
#include <hip/hip_runtime.h>
#include <cmath>

#define BB 64
#define TT 2048
#define FF 64
#define HH 160
#define G3 480
#define TC 128            // time-chunk length
#define NC (TT / TC)      // 16 chunks

typedef unsigned int u32;
typedef _Float16 half8 __attribute__((ext_vector_type(8)));
typedef _Float16 half2v __attribute__((ext_vector_type(2)));
typedef float f32x4 __attribute__((ext_vector_type(4)));

__device__ __forceinline__ unsigned short f2h(float v) {
    _Float16 h = (_Float16)v;
    return __builtin_bit_cast(unsigned short, h);
}
__device__ __forceinline__ u32 packh2(float a, float b) {
    return (u32)f2h(a) | ((u32)f2h(b) << 16);
}
__device__ __forceinline__ float h2lo(u32 p) {
    return (float)__builtin_bit_cast(half2v, p)[0];
}
__device__ __forceinline__ float h2hi(u32 p) {
    return (float)__builtin_bit_cast(half2v, p)[1];
}
__device__ __forceinline__ float fsigmoid(float v) { return 1.f / (1.f + __expf(-v)); }
__device__ __forceinline__ float ftanhf(float v) {
    float xc = fminf(fmaxf(v, -15.f), 15.f);
    float e = __expf(2.f * xc);
    return 1.f - 2.f / (e + 1.f);
}
__device__ __forceinline__ float gelu_exact(float v) {
    return 0.5f * v * (1.f + erff(v * 0.70710678118654752f));
}
// barrier that waits only on LDS ops (NOT vmcnt)
__device__ __forceinline__ void barrier_lgkm() {
    asm volatile("s_waitcnt lgkmcnt(0)\ns_barrier" ::: "memory");
}
__device__ __forceinline__ half8 load_wrow8(const float* p) {
    const float4* q = (const float4*)p;
    float4 a = q[0], b = q[1];
    half8 r;
    r[0] = (_Float16)a.x; r[1] = (_Float16)a.y; r[2] = (_Float16)a.z; r[3] = (_Float16)a.w;
    r[4] = (_Float16)b.x; r[5] = (_Float16)b.y; r[6] = (_Float16)b.z; r[7] = (_Float16)b.w;
    return r;
}
#define MM16(A_, B_, C_) __builtin_amdgcn_mfma_f32_16x16x32_f16(A_, B_, C_, 0, 0, 0)

// ---------------------------------------------------------------------------
// K1: dilated conv + BN + exact GELU -> z f16 [B/16][T][16 chains][64]
// ---------------------------------------------------------------------------
__global__ __launch_bounds__(256) void conv_bn_gelu_kernel(
    const float* __restrict__ x, const float* __restrict__ mix_w,
    const float* __restrict__ bn_g, const float* __restrict__ bn_b,
    const float* __restrict__ bn_m, const float* __restrict__ bn_v,
    u32* __restrict__ z_out)
{
    __shared__ float ws_w[3][64][64];
    __shared__ float ws_x[132][64];
    const int b  = blockIdx.y;
    const int t0 = blockIdx.x * 128;
    const int tid = threadIdx.x;
    const int f  = tid & 63;
    const int rg = tid >> 6;

    for (int idx = tid; idx < 64 * 64 * 3; idx += 256) {
        int fo = idx / 192;
        int rem = idx - fo * 192;
        int fi = rem / 3;
        int k  = rem - fi * 3;
        ws_w[k][fi][fo] = mix_w[idx];
    }
    for (int row = rg; row < 132; row += 4) {
        int t = t0 - 2 + row;
        ws_x[row][f] = (t >= 0 && t < TT) ? x[((size_t)b * TT + t) * FF + f] : 0.f;
    }
    __syncthreads();

    const float scale = bn_g[f] * rsqrtf(bn_v[f] + 1e-5f);
    const float shift = bn_b[f] - bn_m[f] * scale;

    for (int ti = rg; ti < 128; ti += 4) {
        float acc = 0.f;
        #pragma unroll
        for (int k = 0; k < 3; ++k) {
            const float* xr = &ws_x[ti + 2 * k][0];
            #pragma unroll
            for (int fi = 0; fi < 64; ++fi)
                acc = fmaf(xr[fi], ws_w[k][fi][f], acc);
        }
        float y = fmaf(acc, scale, shift);
        float z = gelu_exact(y);
        float zp = __shfl_xor(z, 1);
        if ((f & 1) == 0)
            z_out[(((size_t)(b >> 4) * TT + (t0 + ti)) * 16 + (b & 15)) * 32 + (f >> 1)]
                = packh2(z, zp);
    }
}

// ---------------------------------------------------------------------------
// GEMM device body (MFMA): xg[t][tile][chain][n'/2] f16 pairs. 512 workers.
// ---------------------------------------------------------------------------
#define DECLAI(i) half8 A##i##_0, A##i##_1, A##i##_2, A##i##_3, A##i##_4;
#define GLOADA(i) { int tl = wv4 + (i); int rowc = tl < 30 ? tl * 16 + lane15 : 479; \
    const float* wp = W + (size_t)rowc * K + quad * 8;                               \
    A##i##_0 = load_wrow8(wp); A##i##_1 = load_wrow8(wp + 32);                       \
    if (KT > 2) { A##i##_2 = load_wrow8(wp + 64); A##i##_3 = load_wrow8(wp + 96);    \
                  A##i##_4 = load_wrow8(wp + 128); }                                 \
    else { A##i##_2 = A##i##_0; A##i##_3 = A##i##_0; A##i##_4 = A##i##_0; } }
#define GMM(i, kt) C##i = MM16(A##i##_##kt, Bk##kt, C##i);

template<int K, int KT, int TG>
__device__ __forceinline__ void gemm_body(
    const unsigned short* __restrict__ in,  // f16 [blk][rows][16 chains][K]
    size_t in_blk_stride, int t_off,
    const float* __restrict__ W, const float* __restrict__ b_ih,
    const float* __restrict__ b_hh, u32* __restrict__ xg,
    int gidx, int tid)
{
    if (tid >= 512) return;
    const int wv4 = (tid >> 6) * 4;
    const int lane = tid & 63;
    const int lane15 = lane & 15;
    const int quad = lane >> 4;
    const int blk = gidx >> 4;            // 0..3 chain-block
    const int tbase = (gidx & 15) * TG;   // 16 t-tiles per chunk

    DECLAI(0) DECLAI(1) DECLAI(2) DECLAI(3)
    GLOADA(0) GLOADA(1) GLOADA(2) GLOADA(3)

    f32x4 BIAS0, BIAS1, BIAS2, BIAS3;
    #define GBIAS(i) { int tl = wv4 + (i); int rowb = tl < 30 ? tl * 16 + quad * 4 : 476; \
        float4 bi = *(const float4*)(b_ih + rowb);                                        \
        if (tl < 20) { float4 bh = *(const float4*)(b_hh + rowb);                         \
            bi.x += bh.x; bi.y += bh.y; bi.z += bh.z; bi.w += bh.w; }                     \
        BIAS##i[0] = bi.x; BIAS##i[1] = bi.y; BIAS##i[2] = bi.z; BIAS##i[3] = bi.w; }
    GBIAS(0) GBIAS(1) GBIAS(2) GBIAS(3)
    #undef GBIAS

    const unsigned short* inb = in + (size_t)blk * in_blk_stride;
    u32* xgb = xg + (size_t)blk * TC * 3840;

    for (int t = 0; t < TG; ++t) {
        const int tt = tbase + t;
        const unsigned short* ip =
            inb + ((size_t)(t_off + tt) * 16 + lane15) * K + quad * 8;
        half8 Bk0 = __builtin_bit_cast(half8, *(const uint4*)(ip));
        half8 Bk1 = __builtin_bit_cast(half8, *(const uint4*)(ip + 32));
        half8 Bk2 = Bk0, Bk3 = Bk0, Bk4 = Bk0;
        if (KT > 2) {
            Bk2 = __builtin_bit_cast(half8, *(const uint4*)(ip + 64));
            Bk3 = __builtin_bit_cast(half8, *(const uint4*)(ip + 96));
            Bk4 = __builtin_bit_cast(half8, *(const uint4*)(ip + 128));
        }
        f32x4 C0 = BIAS0, C1 = BIAS1, C2 = BIAS2, C3 = BIAS3;
        GMM(0, 0) GMM(1, 0) GMM(2, 0) GMM(3, 0)
        GMM(0, 1) GMM(1, 1) GMM(2, 1) GMM(3, 1)
        if (KT > 2) {
            GMM(0, 2) GMM(1, 2) GMM(2, 2) GMM(3, 2)
            GMM(0, 3) GMM(1, 3) GMM(2, 3) GMM(3, 3)
            GMM(0, 4) GMM(1, 4) GMM(2, 4) GMM(3, 4)
        }
        #define GSTORE(i) { int tl = wv4 + (i); if (tl < 30) {                      \
            u32 q0 = packh2(C##i[0], C##i[1]);                                      \
            u32 q1 = packh2(C##i[2], C##i[3]);                                      \
            *(uint2*)(xgb + (((size_t)tt * 30 + tl) * 16 + lane15) * 8 + quad * 2)  \
                = (uint2){q0, q1}; } }
        GSTORE(0) GSTORE(1) GSTORE(2) GSTORE(3)
        #undef GSTORE
    }
}

// ---------------------------------------------------------------------------
// Scan device body (MFMA): 640 threads, 10 waves, 16 chains. As R9.
// ---------------------------------------------------------------------------
#define DECLW(nm) half8 nm##0, nm##1, nm##2, nm##3, nm##4;
#define LOADWH(nm, tb) { const float* wp = w_hh + (size_t)((tb) * 16 + lane15) * HH + quad * 8; \
    nm##0 = load_wrow8(wp);       nm##1 = load_wrow8(wp + 32);                                  \
    nm##2 = load_wrow8(wp + 64);  nm##3 = load_wrow8(wp + 96);                                  \
    nm##4 = load_wrow8(wp + 128); }
#define GATE1(CRi, CZi, CNi, XRv, XZv, XNv, BHv, HOc) {     \
    float rr = fsigmoid(CRi + XRv);                         \
    float uu = fsigmoid(CZi + XZv);                         \
    float nn = ftanhf(XNv + rr * (CNi + BHv));              \
    HOc = (1.f - uu) * nn + uu * HOc; }

template<bool WRITE_H>
__device__ __forceinline__ void scan_body(
    const u32* __restrict__ xg,          // f16 pairs [4][TC][30][16][8] u32
    const float* __restrict__ w_hh, const float* __restrict__ b_hh,
    float* __restrict__ h_state,         // [64][160] f32 carry
    u32* __restrict__ h_out32,           // [4][TC][16][80] u32 (if WRITE_H)
    int first, int blk, int tid, uint4* h_lds)
{
    const int wv = tid >> 6;
    const int lane = tid & 63;
    const int lane15 = lane & 15;
    const int quad = lane >> 4;

    DECLW(Ar) DECLW(Az) DECLW(An)
    LOADWH(Ar, wv) LOADWH(Az, 10 + wv) LOADWH(An, 20 + wv)

    const float4 bhn = *(const float4*)(b_hh + 320 + wv * 16 + quad * 4);

    float4 ho = {0.f, 0.f, 0.f, 0.f};
    float* hsp = h_state + (size_t)(blk * 16 + lane15) * HH;
    if (!first) ho = *(const float4*)(hsp + wv * 16 + quad * 4);

    const int hwidx = (((wv >> 1) * 4 + ((wv & 1) * 2 + (quad >> 1))) * 16 + lane15) * 4
                    + (quad & 1) * 2;
    u32* hl32 = (u32*)h_lds;
    hl32[hwidx]     = packh2(ho.x, ho.y);
    hl32[hwidx + 1] = packh2(ho.z, ho.w);

    const u32* xgb = xg + (size_t)blk * TC * 3840;
    const int xo_r = ((wv)      * 16 + lane15) * 8 + quad * 2;
    const int xo_z = ((10 + wv) * 16 + lane15) * 8 + quad * 2;
    const int xo_n = ((20 + wv) * 16 + lane15) * 8 + quad * 2;

    uint2 xr = *(const uint2*)(xgb + xo_r);
    uint2 xz = *(const uint2*)(xgb + xo_z);
    uint2 xn = *(const uint2*)(xgb + xo_n);

    u32* ho32 = h_out32 + (WRITE_H ? (size_t)blk * TC * 1280 : 0);
    __syncthreads();

    for (int t = 0; t < TC; ++t) {
        const uint4* hb = h_lds + (t & 1) * 320;
        uint4 b0 = hb[lane];
        uint4 b1 = hb[64 + lane];
        uint4 b2 = hb[128 + lane];
        uint4 b3 = hb[192 + lane];
        uint4 b4 = hb[256 + lane];

        const int tn = (t + 1 < TC) ? t + 1 : t;
        const u32* xgt = xgb + (size_t)tn * 3840;
        uint2 xr_n = *(const uint2*)(xgt + xo_r);
        uint2 xz_n = *(const uint2*)(xgt + xo_z);
        uint2 xn_n = *(const uint2*)(xgt + xo_n);

        f32x4 Cr = {0.f, 0.f, 0.f, 0.f};
        f32x4 Cz = {0.f, 0.f, 0.f, 0.f};
        f32x4 Cn = {0.f, 0.f, 0.f, 0.f};
        half8 B0 = __builtin_bit_cast(half8, b0);
        Cr = MM16(Ar0, B0, Cr); Cz = MM16(Az0, B0, Cz); Cn = MM16(An0, B0, Cn);
        half8 B1 = __builtin_bit_cast(half8, b1);
        Cr = MM16(Ar1, B1, Cr); Cz = MM16(Az1, B1, Cz); Cn = MM16(An1, B1, Cn);
        half8 B2 = __builtin_bit_cast(half8, b2);
        Cr = MM16(Ar2, B2, Cr); Cz = MM16(Az2, B2, Cz); Cn = MM16(An2, B2, Cn);
        half8 B3 = __builtin_bit_cast(half8, b3);
        Cr = MM16(Ar3, B3, Cr); Cz = MM16(Az3, B3, Cz); Cn = MM16(An3, B3, Cn);
        half8 B4 = __builtin_bit_cast(half8, b4);
        Cr = MM16(Ar4, B4, Cr); Cz = MM16(Az4, B4, Cz); Cn = MM16(An4, B4, Cn);

        GATE1(Cr[0], Cz[0], Cn[0], h2lo(xr.x), h2lo(xz.x), h2lo(xn.x), bhn.x, ho.x)
        GATE1(Cr[1], Cz[1], Cn[1], h2hi(xr.x), h2hi(xz.x), h2hi(xn.x), bhn.y, ho.y)
        GATE1(Cr[2], Cz[2], Cn[2], h2lo(xr.y), h2lo(xz.y), h2lo(xn.y), bhn.z, ho.z)
        GATE1(Cr[3], Cz[3], Cn[3], h2hi(xr.y), h2hi(xz.y), h2hi(xn.y), bhn.w, ho.w)

        const u32 p0 = packh2(ho.x, ho.y);
        const u32 p1 = packh2(ho.z, ho.w);
        u32* hw = hl32 + ((t + 1) & 1) * 1280;
        hw[hwidx]     = p0;
        hw[hwidx + 1] = p1;
        if (WRITE_H) {
            u32* hp = ho32 + (size_t)(t * 16 + lane15) * 80;
            hp[wv * 8 + quad * 2]     = p0;
            hp[wv * 8 + quad * 2 + 1] = p1;
        }
        barrier_lgkm();
        xr = xr_n; xz = xz_n; xn = xn_n;
    }
    *(float4*)(hsp + wv * 16 + quad * 4) = ho;
}

// ---------------------------------------------------------------------------
// K2: pipelined mega-dispatch. Stage k runs concurrently:
//   blocks 0..3    : scan1 chunk k-1
//   blocks 4..7    : scan2 chunk k-3
//   blocks 8..71   : gemm1 chunk k      (64 blocks, TG=8)
//   blocks 72..135 : gemm2 chunk k-2    (64 blocks, TG=8)
// All producer->consumer edges cross a dispatch boundary; parity (chunk&1)
// double-buffers xg1/xg2/h1c against same-dispatch writers.
// ---------------------------------------------------------------------------
__global__ __launch_bounds__(640) void pipe_stage(
    const u32* __restrict__ z,           // [4][TT][16][32] u32
    u32* __restrict__ xg1,               // 2 x [4][TC][3840] u32
    u32* __restrict__ xg2,
    u32* __restrict__ h1c,               // 2 x [4][TC][1280] u32
    float* __restrict__ h1s, float* __restrict__ h2s,
    const float* __restrict__ w_ih1, const float* __restrict__ b_ih1,
    const float* __restrict__ w_hh1, const float* __restrict__ b_hh1,
    const float* __restrict__ w_ih2, const float* __restrict__ b_ih2,
    const float* __restrict__ w_hh2, const float* __restrict__ b_hh2,
    int k)
{
    __shared__ uint4 h_lds[2 * 320];
    const int bx = blockIdx.x;
    const int tid = threadIdx.x;
    const size_t XGCH = (size_t)4 * TC * 3840;   // u32 per parity buffer
    const size_t H1CH = (size_t)4 * TC * 1280;

    if (bx < 4) {
        const int c = k - 1;
        if (c < 0 || c >= NC) return;
        scan_body<true>(xg1 + (c & 1) * XGCH, w_hh1, b_hh1, h1s,
                        h1c + (c & 1) * H1CH, c == 0, bx, tid, h_lds);
    } else if (bx < 8) {
        const int c = k - 3;
        if (c < 0 || c >= NC) return;
        scan_body<false>(xg2 + (c & 1) * XGCH, w_hh2, b_hh2, h2s,
                         nullptr, c == 0, bx - 4, tid, h_lds);
    } else if (bx < 72) {
        const int c = k;
        if (c >= NC) return;
        gemm_body<64, 2, 8>((const unsigned short*)z, (size_t)TT * 1024, c * TC,
                            w_ih1, b_ih1, b_hh1, xg1 + (c & 1) * XGCH, bx - 8, tid);
    } else {
        const int c = k - 2;
        if (c < 0 || c >= NC) return;
        gemm_body<160, 5, 8>((const unsigned short*)(h1c + (c & 1) * H1CH),
                             (size_t)TC * 2560, 0,
                             w_ih2, b_ih2, b_hh2, xg2 + (c & 1) * XGCH, bx - 72, tid);
    }
}

// ---------------------------------------------------------------------------
// K3: MLP head from h2 final state.
// ---------------------------------------------------------------------------
__global__ __launch_bounds__(256) void head_kernel(
    const float* __restrict__ h_state,
    const float* __restrict__ hw1, const float* __restrict__ hb1,
    const float* __restrict__ hw2, const float* __restrict__ hb2,
    float* __restrict__ out)
{
    const int b = blockIdx.x;
    const int tid = threadIdx.x;
    __shared__ float hf[HH];
    __shared__ float q[80];
    if (tid < HH) hf[tid] = h_state[b * HH + tid];
    __syncthreads();
    if (tid < 80) {
        float a = hb1[tid];
        const float* wr = hw1 + (size_t)tid * HH;
        #pragma unroll 8
        for (int i = 0; i < HH; ++i) a = fmaf(wr[i], hf[i], a);
        q[tid] = gelu_exact(a);
    }
    __syncthreads();
    if (tid < 2) {
        float o = hb2[tid];
        const float* wr = hw2 + tid * 80;
        #pragma unroll 8
        for (int j = 0; j < 80; ++j) o = fmaf(wr[j], q[j], o);
        out[b * 2 + tid] = o;
    }
}

// ---------------------------------------------------------------------------
extern "C" void kernel_launch(void* const* d_in, const int* in_sizes, int n_in,
                              void* d_out, int out_size, void* d_ws, size_t ws_size,
                              hipStream_t stream)
{
    const float* x     = (const float*)d_in[0];
    const float* mix_w = (const float*)d_in[1];
    const float* bn_g  = (const float*)d_in[2];
    const float* bn_b  = (const float*)d_in[3];
    const float* bn_m  = (const float*)d_in[4];
    const float* bn_v  = (const float*)d_in[5];
    const float* w_ih1 = (const float*)d_in[6];
    const float* w_hh1 = (const float*)d_in[7];
    const float* b_ih1 = (const float*)d_in[8];
    const float* b_hh1 = (const float*)d_in[9];
    const float* w_ih2 = (const float*)d_in[10];
    const float* w_hh2 = (const float*)d_in[11];
    const float* b_ih2 = (const float*)d_in[12];
    const float* b_hh2 = (const float*)d_in[13];
    const float* hw1   = (const float*)d_in[14];
    const float* hb1   = (const float*)d_in[15];
    const float* hw2   = (const float*)d_in[16];
    const float* hb2   = (const float*)d_in[17];
    float* out = (float*)d_out;

    // ws (53.6 MB, proven-safe):
    //   z    f16 [4][T][16][64]            16.78 MB
    //   xg1  f16 2x[4][TC][30][16][16]     15.73 MB
    //   xg2  f16 2x[4][TC][30][16][16]     15.73 MB
    //   h1c  f16 2x[4][TC][16][160]         5.24 MB
    //   h1s,h2s f32 [64][160]               2 x 40 KB
    char* p = (char*)d_ws;
    u32* z_ws  = (u32*)p;  p += (size_t)BB * TT * 32 * 4;
    u32* xg1_ws = (u32*)p; p += (size_t)2 * 4 * TC * 3840 * 4;
    u32* xg2_ws = (u32*)p; p += (size_t)2 * 4 * TC * 3840 * 4;
    u32* h1c_ws = (u32*)p; p += (size_t)2 * 4 * TC * 1280 * 4;
    float* h1s = (float*)p; p += (size_t)BB * HH * 4;
    float* h2s = (float*)p;

    conv_bn_gelu_kernel<<<dim3(16, BB), 256, 0, stream>>>(
        x, mix_w, bn_g, bn_b, bn_m, bn_v, z_ws);

    for (int k = 0; k <= NC + 2; ++k) {
        pipe_stage<<<136, 640, 0, stream>>>(
            z_ws, xg1_ws, xg2_ws, h1c_ws, h1s, h2s,
            w_ih1, b_ih1, w_hh1, b_hh1,
            w_ih2, b_ih2, w_hh2, b_hh2, k);
    }

    head_kernel<<<BB, 256, 0, stream>>>(h2s, hw1, hb1, hw2, hb2, out);
}